// Round 6
// baseline (649.676 us; speedup 1.0000x reference)
//
#include <hip/hip_runtime.h>
#include <math.h>

// Problem constants (B=8, S=2048, D=1024, DK=DV=128, FF=4096)
#define M_TOT   16384
#define D_MODEL 1024
#define D_HEAD  128
#define SEQ     2048
#define NBATCH  8
#define D_FF    4096

typedef _Float16 f16x8 __attribute__((ext_vector_type(8)));
typedef _Float16 f16x4 __attribute__((ext_vector_type(4)));
typedef float    f32x4 __attribute__((ext_vector_type(4)));

#define ATT_SCALE 0.08838834764831845f  // 1/sqrt(128)

__device__ __forceinline__ void gload_lds16(const _Float16* g, _Float16* l) {
  __builtin_amdgcn_global_load_lds(
      (const __attribute__((address_space(1))) unsigned int*)g,
      (__attribute__((address_space(3))) unsigned int*)l, 16, 0, 0);
}
__device__ __forceinline__ unsigned short f16bits(float v) {
  union { _Float16 f; unsigned short u; } cv; cv.f = (_Float16)v; return cv.u;
}
// tanh-form GELU: 0.5x(1+tanh(0.79788456(x+0.044715x^3))); overflow-safe, ~8 VALU ops
__device__ __forceinline__ float gelu_f(float x) {
  const float t = 0.7978845608028654f * x * (1.0f + 0.044715f * x * x);
  const float e = __expf(2.0f * t);
  const float th = 1.0f - 2.0f / (e + 1.0f);
  return 0.5f * x * (1.0f + th);
}
__device__ __forceinline__ void bar_sync() {
  __asm__ volatile("" ::: "memory");
  __builtin_amdgcn_s_barrier();
  __asm__ volatile("" ::: "memory");
}
// raw ds_read_b128 with immediate offset
__device__ __forceinline__ void ds_read128o(f16x8& d, unsigned addr, int imm) {
  asm volatile("ds_read_b128 %0, %1 offset:%2" : "=v"(d) : "v"(addr), "i"(imm));
}
#define MFMA16(a, b, c) __builtin_amdgcn_mfma_f32_16x16x32_f16((a), (b), (c), 0, 0, 0)

// ---------------- weight convert + transpose: out[n][k] = f16(in[k][n]) ----------------
__global__ __launch_bounds__(256) void convt_kernel(const float* __restrict__ in,
                                                    _Float16* __restrict__ out,
                                                    int K, int N) {
  __shared__ float t[32][33];
  const int n0 = blockIdx.x * 32, k0 = blockIdx.y * 32;
  const int tx = threadIdx.x & 31, ty = threadIdx.x >> 5;   // 32 x 8
#pragma unroll
  for (int r = 0; r < 4; r++)
    t[ty + 8 * r][tx] = in[(size_t)(k0 + ty + 8 * r) * N + n0 + tx];
  __syncthreads();
#pragma unroll
  for (int r = 0; r < 4; r++)
    out[(size_t)(n0 + ty + 8 * r) * K + k0 + tx] = (_Float16)t[tx][ty + 8 * r];
}

// ---------------- LayerNorm: one block (256 thr) per row of 1024 ----------------
template <bool WF32>
__global__ __launch_bounds__(256) void ln_kernel(const float* __restrict__ in,
                                                 const float* __restrict__ gamma,
                                                 const float* __restrict__ beta,
                                                 float* __restrict__ of,
                                                 _Float16* __restrict__ oh) {
  __shared__ float shs[4], shq[4];
  const int row = blockIdx.x;
  const int t = threadIdx.x;
  float4 v = ((const float4*)(in + (size_t)row * D_MODEL))[t];
  float s = v.x + v.y + v.z + v.w;
  float q = v.x * v.x + v.y * v.y + v.z * v.z + v.w * v.w;
#pragma unroll
  for (int o = 32; o > 0; o >>= 1) {
    s += __shfl_down(s, o, 64);
    q += __shfl_down(q, o, 64);
  }
  const int lane = t & 63, w = t >> 6;
  if (lane == 0) { shs[w] = s; shq[w] = q; }
  __syncthreads();
  if (t == 0) {
    shs[0] = shs[0] + shs[1] + shs[2] + shs[3];
    shq[0] = shq[0] + shq[1] + shq[2] + shq[3];
  }
  __syncthreads();
  const float mu = shs[0] * (1.0f / D_MODEL);
  const float var = shq[0] * (1.0f / D_MODEL) - mu * mu;
  const float rs = rsqrtf(var + 1e-5f);
  float4 gv = ((const float4*)gamma)[t];
  float4 bv = ((const float4*)beta)[t];
  float4 o;
  o.x = (v.x - mu) * rs * gv.x + bv.x;
  o.y = (v.y - mu) * rs * gv.y + bv.y;
  o.z = (v.z - mu) * rs * gv.z + bv.z;
  o.w = (v.w - mu) * rs * gv.w + bv.w;
  if (WF32) ((float4*)(of + (size_t)row * D_MODEL))[t] = o;
  f16x4 h4 = {(_Float16)o.x, (_Float16)o.y, (_Float16)o.z, (_Float16)o.w};
  ((f16x4*)(oh + (size_t)row * D_MODEL))[t] = h4;
}

// =====================================================================================
// 256x256-tile MFMA GEMM, BK=32, 512 thr = 8 waves (2Mx4N), 4-slot LDS ring (128 KiB).
// 4-phase fine-grained K-tile schedule (m201 mechanism): per phase, JIT frag ds_reads
// + 1 staging gload (tile JT+3) + barrier + lgkmcnt(0) + setprio'd 8-MFMA cluster +
// barrier. Counted vmcnt(8) once per tile (JIT reads need only tile JT+1 landed).
// XOR-swizzled LDS (T2, verified), XCD-aware block swizzle (T1).
// A f16 [M][K], BT f16 [N][K].
// MODE 0: C f32 = acc + bias[col] + res ; MODE 1: C f16 = gelu(acc + bias[col])
// Requires: M%256==0, N%256==0, K%128==0 (NKT>=4), gridDim.x%8==0.
// =====================================================================================

// one 1-KiB staging gload each (16 rows x 32 f16); FIFO order per tile: A1,A2,B1,B2.
#define STG_A1(JT) gload_lds16(Ag0 + (size_t)(JT) * 32, SM + (((JT) & 3) * 16384) + ldsA)
#define STG_A2(JT) gload_lds16(Ag0 + 16 * (size_t)K + (size_t)(JT) * 32, SM + (((JT) & 3) * 16384) + ldsA + 512)
#define STG_B1(JT) gload_lds16(Bg0 + (size_t)(JT) * 32, SM + (((JT) & 3) * 16384) + ldsB)
#define STG_B2(JT) gload_lds16(Bg0 + 16 * (size_t)K + (size_t)(JT) * 32, SM + (((JT) & 3) * 16384) + ldsB + 512)

// vmcnt ledger (per wave, 4 gloads/tile): at iter JT bottom, outstanding = tiles
// JT+1..JT+3 (12). Next iter's JIT reads touch ONLY tile JT+1 -> vmcnt(8) retires it.
// Per-wave vmcnt + barrier = collective landed-guarantee (each wave stages its own rows).
#define KITER4(JT, PF, WVM)                                                         \
  {                                                                                 \
    const unsigned sb_ = ((unsigned)((JT) & 3)) << 15;                              \
    const unsigned bA_ = fbaseA + sb_;                                              \
    const unsigned bB_ = fbaseB + sb_;                                              \
    f16x8 fa0, fa1, fa2, fa3, fa4, fa5, fa6, fa7, fb0, fb1, fb2, fb3;               \
    /* phase 1: reads A0-3,B0-1 ; stage A1(JT+3) ; MFMA m0-3 x n0-1 */              \
    ds_read128o(fa0, bA_, 0);    ds_read128o(fa1, bA_, 1024);                       \
    ds_read128o(fa2, bA_, 2048); ds_read128o(fa3, bA_, 3072);                       \
    ds_read128o(fb0, bB_, 0);    ds_read128o(fb1, bB_, 1024);                       \
    if (PF) { STG_A1((JT) + 3); }                                                   \
    bar_sync();                                                                     \
    asm volatile("s_waitcnt lgkmcnt(0)" ::: "memory");                              \
    __builtin_amdgcn_sched_barrier(0);                                              \
    __builtin_amdgcn_s_setprio(1);                                                  \
    acc[0][0] = MFMA16(fa0, fb0, acc[0][0]); acc[0][1] = MFMA16(fa0, fb1, acc[0][1]); \
    acc[1][0] = MFMA16(fa1, fb0, acc[1][0]); acc[1][1] = MFMA16(fa1, fb1, acc[1][1]); \
    acc[2][0] = MFMA16(fa2, fb0, acc[2][0]); acc[2][1] = MFMA16(fa2, fb1, acc[2][1]); \
    acc[3][0] = MFMA16(fa3, fb0, acc[3][0]); acc[3][1] = MFMA16(fa3, fb1, acc[3][1]); \
    __builtin_amdgcn_s_setprio(0);                                                  \
    bar_sync();                                                                     \
    /* phase 2: reads B2-3 ; stage A2(JT+3) ; MFMA m0-3 x n2-3 */                   \
    ds_read128o(fb2, bB_, 2048); ds_read128o(fb3, bB_, 3072);                       \
    if (PF) { STG_A2((JT) + 3); }                                                   \
    bar_sync();                                                                     \
    asm volatile("s_waitcnt lgkmcnt(0)" ::: "memory");                              \
    __builtin_amdgcn_sched_barrier(0);                                              \
    __builtin_amdgcn_s_setprio(1);                                                  \
    acc[0][2] = MFMA16(fa0, fb2, acc[0][2]); acc[0][3] = MFMA16(fa0, fb3, acc[0][3]); \
    acc[1][2] = MFMA16(fa1, fb2, acc[1][2]); acc[1][3] = MFMA16(fa1, fb3, acc[1][3]); \
    acc[2][2] = MFMA16(fa2, fb2, acc[2][2]); acc[2][3] = MFMA16(fa2, fb3, acc[2][3]); \
    acc[3][2] = MFMA16(fa3, fb2, acc[3][2]); acc[3][3] = MFMA16(fa3, fb3, acc[3][3]); \
    __builtin_amdgcn_s_setprio(0);                                                  \
    bar_sync();                                                                     \
    /* phase 3: reads A4-7 ; stage B1(JT+3) ; MFMA m4-7 x n0-1 */                   \
    ds_read128o(fa4, bA_, 4096); ds_read128o(fa5, bA_, 5120);                       \
    ds_read128o(fa6, bA_, 6144); ds_read128o(fa7, bA_, 7168);                       \
    if (PF) { STG_B1((JT) + 3); }                                                   \
    bar_sync();                                                                     \
    asm volatile("s_waitcnt lgkmcnt(0)" ::: "memory");                              \
    __builtin_amdgcn_sched_barrier(0);                                              \
    __builtin_amdgcn_s_setprio(1);                                                  \
    acc[4][0] = MFMA16(fa4, fb0, acc[4][0]); acc[4][1] = MFMA16(fa4, fb1, acc[4][1]); \
    acc[5][0] = MFMA16(fa5, fb0, acc[5][0]); acc[5][1] = MFMA16(fa5, fb1, acc[5][1]); \
    acc[6][0] = MFMA16(fa6, fb0, acc[6][0]); acc[6][1] = MFMA16(fa6, fb1, acc[6][1]); \
    acc[7][0] = MFMA16(fa7, fb0, acc[7][0]); acc[7][1] = MFMA16(fa7, fb1, acc[7][1]); \
    __builtin_amdgcn_s_setprio(0);                                                  \
    bar_sync();                                                                     \
    /* phase 4: no reads ; stage B2(JT+3) ; MFMA m4-7 x n2-3 ; counted vmcnt */     \
    if (PF) { STG_B2((JT) + 3); }                                                   \
    bar_sync();                                                                     \
    __builtin_amdgcn_s_setprio(1);                                                  \
    acc[4][2] = MFMA16(fa4, fb2, acc[4][2]); acc[4][3] = MFMA16(fa4, fb3, acc[4][3]); \
    acc[5][2] = MFMA16(fa5, fb2, acc[5][2]); acc[5][3] = MFMA16(fa5, fb3, acc[5][3]); \
    acc[6][2] = MFMA16(fa6, fb2, acc[6][2]); acc[6][3] = MFMA16(fa6, fb3, acc[6][3]); \
    acc[7][2] = MFMA16(fa7, fb2, acc[7][2]); acc[7][3] = MFMA16(fa7, fb3, acc[7][3]); \
    __builtin_amdgcn_s_setprio(0);                                                  \
    if ((WVM) == 8) { asm volatile("s_waitcnt vmcnt(8)" ::: "memory"); bar_sync(); } \
    if ((WVM) == 4) { asm volatile("s_waitcnt vmcnt(4)" ::: "memory"); bar_sync(); } \
    if ((WVM) == 0) { asm volatile("s_waitcnt vmcnt(0)" ::: "memory"); bar_sync(); } \
  }

template <int MODE>
__global__ __launch_bounds__(512, 2) void mfma_gemm256(
    const _Float16* __restrict__ A, const _Float16* __restrict__ BT,
    const float* __restrict__ bias, const float* __restrict__ res,
    void* __restrict__ Cout, int M, int N, int K) {
  __shared__ __attribute__((aligned(16))) _Float16 SM[4 * 16384];  // 4 ring slots x (A 8192 | B 8192) f16
  const int tid = threadIdx.x;
  const int lane = tid & 63, w = tid >> 6;
  const int l15 = lane & 15, quad = lane >> 4;
  const int wm = w >> 2, wn = w & 3;

  // T1: XCD-aware swizzle (consecutive logical ids -> same XCD; gridDim.x%8==0)
  const int nwg = gridDim.x;
  const int bid = (blockIdx.x & 7) * (nwg >> 3) + (blockIdx.x >> 3);
  const int nbx = N >> 8;
  const int bx = bid % nbx, by = bid / nbx;
  const int row0 = by << 8, col0 = bx << 8;

  // per-lane pre-swizzled global source for the linear-dest global_load_lds:
  // lane L writes LDS phys slot (rp=L>>3, e=L&7); logical = sigma(phys).
  const int rp = lane >> 3;
  const int el = (lane & 7) ^ rp;
  const int lr = (rp << 1) | (el >> 2);   // logical row in 16-row group
  const int lc = (el & 3) << 3;           // logical f16 col offset
  const _Float16* Ag0 = A + (size_t)(row0 + w * 32 + lr) * K + lc;
  const _Float16* Bg0 = BT + (size_t)(col0 + w * 32 + lr) * K + lc;
  const int ldsA = w * 1024;
  const int ldsB = 8192 + w * 1024;

  // fragment-read bases (verified round 4): A block wm*128 rows -> wm*8192 B;
  // B block wn*64 rows -> wn*4096 B; swizzle lane terms m/n-independent.
  const unsigned lds0 =
      (unsigned)(size_t)(__attribute__((address_space(3))) _Float16*)&SM[0];
  const unsigned esw = (unsigned)((((l15 & 1) << 2) | quad) ^ ((l15 >> 1) & 7));
  const unsigned rl128 = (unsigned)(l15 >> 1) << 7;
  const unsigned fbaseA = lds0 + (unsigned)(wm * 8192) + rl128 + (esw << 4);
  const unsigned fbaseB = lds0 + 16384u + (unsigned)(wn * 4096) + rl128 + (esw << 4);

  const f32x4 zero = {0.f, 0.f, 0.f, 0.f};
  f32x4 acc[8][4];
#pragma unroll
  for (int m = 0; m < 8; ++m)
#pragma unroll
    for (int n = 0; n < 4; ++n) acc[m][n] = zero;

  const int NKT = K >> 5;   // >= 4

  // prologue: stage K-tiles 0..2 (12 loads, FIFO A1,A2,B1,B2 per tile);
  // vmcnt(8)+barrier = tile 0 landed collectively.
  for (int t = 0; t < 3; ++t) { STG_A1(t); STG_A2(t); STG_B1(t); STG_B2(t); }
  asm volatile("s_waitcnt vmcnt(8)" ::: "memory");
  bar_sync();

  int j = 0;
#pragma unroll 1
  for (; j + 3 < NKT; ++j) { KITER4(j, 1, 8); }
  // tail ledger: iter NKT-3: outstanding 8 (tiles NKT-2,NKT-1) -> vmcnt(4);
  // iter NKT-2: outstanding 4 -> vmcnt(0); iter NKT-1: nothing outstanding.
  KITER4(NKT - 3, 0, 4);
  KITER4(NKT - 2, 0, 0);
  KITER4(NKT - 1, 0, -1);

  // epilogue. C/D layout: col = l15, row = quad*4 + r  [verified earlier rounds]
  const int colb = col0 + wn * 64 + l15;
  if (MODE == 0) {
    float* C = (float*)Cout;
    float bv[4];
#pragma unroll
    for (int n = 0; n < 4; ++n) bv[n] = bias[colb + n * 16];
#pragma unroll
    for (int m = 0; m < 8; ++m)
#pragma unroll
      for (int r = 0; r < 4; ++r) {
        const int row = row0 + wm * 128 + m * 16 + quad * 4 + r;
        const size_t base = (size_t)row * N + colb;
        const float* rp2 = res + base;
        float* cp = C + base;
#pragma unroll
        for (int n = 0; n < 4; ++n) cp[n * 16] = acc[m][n][r] + bv[n] + rp2[n * 16];
      }
  } else {
    _Float16* C = (_Float16*)Cout;
    float bv[4];
#pragma unroll
    for (int n = 0; n < 4; ++n) bv[n] = bias[colb + n * 16];
#pragma unroll
    for (int m = 0; m < 8; ++m)
#pragma unroll
      for (int r = 0; r < 4; ++r) {
        const int row = row0 + wm * 128 + m * 16 + quad * 4 + r;
        _Float16* cp = C + (size_t)row * N + colb;
#pragma unroll
        for (int n = 0; n < 4; ++n) cp[n * 16] = (_Float16)gelu_f(acc[m][n][r] + bv[n]);
      }
  }
  (void)M;
}

// ---------------- old 128x128 MFMA GEMM (kept for fused QKV, MODE 2) ----------------
template <int MODE>
__global__ __launch_bounds__(256) void mfma_gemm(const _Float16* __restrict__ A,
                                                 const _Float16* __restrict__ BT,
                                                 const float* __restrict__ b0p,
                                                 const float* __restrict__ b1p,
                                                 const float* __restrict__ b2p,
                                                 const float* __restrict__ res,
                                                 void* __restrict__ Cout,
                                                 _Float16* __restrict__ vtout,
                                                 int M, int N, int K) {
  __shared__ _Float16 SMEM[2 * 128 * 32];   // As | Bs ; aliased as Ts in MODE2-V epilogue
  _Float16* As = SMEM;
  _Float16* Bs = SMEM + 128 * 32;
  const int tid = threadIdx.x;
  const int lane = tid & 63, w = tid >> 6;
  const int wr = w >> 1, wc = w & 1;
  const int row0 = blockIdx.y << 7, col0 = blockIdx.x << 7;
  const int l15 = lane & 15, quad = lane >> 4;
  const f32x4 zero = {0.f, 0.f, 0.f, 0.f};
  f32x4 acc[4][4];
#pragma unroll
  for (int i = 0; i < 4; i++)
#pragma unroll
    for (int j = 0; j < 4; j++) acc[i][j] = zero;

  const int srow = lane >> 2;          // 0..15
  const int scol = (lane & 3) << 3;    // 0,8,16,24
  const _Float16* Ag = A + (size_t)(row0 + w * 32 + srow) * K + scol;
  const _Float16* Bg = BT + (size_t)(col0 + w * 32 + srow) * K + scol;

  for (int k0 = 0; k0 < K; k0 += 32) {
#pragma unroll
    for (int p = 0; p < 2; p++) {
      gload_lds16(Ag + (size_t)(p * 16) * K + k0, &As[(w * 32 + p * 16) * 32]);
      gload_lds16(Bg + (size_t)(p * 16) * K + k0, &Bs[(w * 32 + p * 16) * 32]);
    }
    __syncthreads();
    f16x8 af[4], bfr[4];
#pragma unroll
    for (int i = 0; i < 4; i++) {
      af[i]  = *(const f16x8*)&As[(wr * 64 + i * 16 + l15) * 32 + quad * 8];
      bfr[i] = *(const f16x8*)&Bs[(wc * 64 + i * 16 + l15) * 32 + quad * 8];
    }
#pragma unroll
    for (int i = 0; i < 4; i++)
#pragma unroll
      for (int j = 0; j < 4; j++)
        acc[i][j] = __builtin_amdgcn_mfma_f32_16x16x32_f16(af[i], bfr[j], acc[i][j], 0, 0, 0);
    __syncthreads();
  }

  // Epilogue. C/D layout: col = l15, row = quad*4 + r
  if (MODE == 0) {
    float* C = (float*)Cout;
    float bv4[4];
#pragma unroll
    for (int j = 0; j < 4; j++) bv4[j] = b0p[col0 + wc * 64 + j * 16 + l15];
#pragma unroll
    for (int i = 0; i < 4; i++)
#pragma unroll
      for (int r = 0; r < 4; r++) {
        const int row = row0 + wr * 64 + i * 16 + quad * 4 + r;
        const size_t base = (size_t)row * N + col0 + wc * 64 + l15;
        const float* rp = res + base;
        float* cp = C + base;
#pragma unroll
        for (int j = 0; j < 4; j++)
          cp[j * 16] = acc[i][j][r] + bv4[j] + rp[j * 16];
      }
  } else if (MODE == 1) {
    _Float16* C = (_Float16*)Cout;
    float bv4[4];
#pragma unroll
    for (int j = 0; j < 4; j++) bv4[j] = b0p[col0 + wc * 64 + j * 16 + l15];
#pragma unroll
    for (int i = 0; i < 4; i++)
#pragma unroll
      for (int r = 0; r < 4; r++) {
        const int row = row0 + wr * 64 + i * 16 + quad * 4 + r;
        _Float16* cp = C + (size_t)row * N + col0 + wc * 64 + l15;
#pragma unroll
        for (int j = 0; j < 4; j++)
          cp[j * 16] = (_Float16)gelu_f(acc[i][j][r] + bv4[j]);
      }
  } else {
    _Float16* qkout = (_Float16*)Cout;
    const int bx = blockIdx.x;
    if (bx < 2) {
      // q (scaled) or k -> qk[M][256]
      const float* bp = (bx == 0) ? b0p : b1p;
      const float sc = (bx == 0) ? ATT_SCALE : 1.0f;
      const int cofs = bx * 128 + wc * 64 + l15;
      float bv4[4];
#pragma unroll
      for (int j = 0; j < 4; j++) bv4[j] = bp[wc * 64 + j * 16 + l15];
#pragma unroll
      for (int i = 0; i < 4; i++)
#pragma unroll
        for (int r = 0; r < 4; r++) {
          const int row = row0 + wr * 64 + i * 16 + quad * 4 + r;
          _Float16* cp = qkout + (size_t)row * 256 + cofs;
#pragma unroll
          for (int j = 0; j < 4; j++)
            cp[j * 16] = (_Float16)((acc[i][j][r] + bv4[j]) * sc);
        }
    } else {
      // v -> vt[B][128][S], via LDS transpose (Ts[vd][40] f16, aliases SMEM)
      _Float16* Ts = SMEM;
      float bv4[4];
#pragma unroll
      for (int j = 0; j < 4; j++) bv4[j] = b2p[wc * 64 + j * 16 + l15];
      const int bb = row0 >> 11, s0 = row0 & 2047;
#pragma unroll
      for (int c = 0; c < 4; c++) {        // s-chunk [c*32, c*32+32)
        __syncthreads();
        if (wr == (c >> 1)) {
#pragma unroll
          for (int ii = 0; ii < 2; ii++) {
            const int i = (c & 1) * 2 + ii;
#pragma unroll
            for (int j = 0; j < 4; j++) {
              const int vd = wc * 64 + j * 16 + l15;
              const int slocal = ii * 16 + quad * 4;
              ushort4 h;
              h.x = f16bits(acc[i][j][0] + bv4[j]);
              h.y = f16bits(acc[i][j][1] + bv4[j]);
              h.z = f16bits(acc[i][j][2] + bv4[j]);
              h.w = f16bits(acc[i][j][3] + bv4[j]);
              *(ushort4*)&Ts[vd * 40 + slocal] = h;
            }
          }
        }
        __syncthreads();
#pragma unroll
        for (int p = 0; p < 2; p++) {
          const int idx = tid + p * 256;       // 0..511
          const int vd = idx >> 2, s8 = (idx & 3) * 8;
          uint4 d = *(const uint4*)&Ts[vd * 40 + s8];
          *(uint4*)&vtout[((size_t)bb * 128 + vd) * SEQ + s0 + c * 32 + s8] = d;
        }
      }
    }
  }
}

// ---------------- MFMA flash attention ----------------
// Grid (SEQ/64, B), 256 thr = 4 waves, 16 queries/wave. 64-key tiles.
// qk: [B*S][256] f16 (q pre-scaled, k). vt: [B][128][S] f16. H: [B*S][128] f16.
__global__ __launch_bounds__(256) void flash_attn_mfma(const _Float16* __restrict__ qk,
                                                       const _Float16* __restrict__ vt,
                                                       _Float16* __restrict__ H) {
  __shared__ _Float16 Ks[2][64][136];   // keys x d, pad 8
  __shared__ _Float16 Vs[128][72];      // d x keys, pad 8
  __shared__ _Float16 Ps[4][16][72];    // per-wave P: q x keys, pad 8
  const int b = blockIdx.y, q0 = blockIdx.x * 64;
  const int tid = threadIdx.x;
  const int lane = tid & 63, w = tid >> 6;
  const int l15 = lane & 15, quad = lane >> 4;

  // Q fragments (A-layout), q pre-scaled by 1/sqrt(dk)
  f16x8 qf[4];
  {
    const _Float16* qrow = qk + ((size_t)(b * SEQ + q0 + w * 16 + l15)) * 256 + quad * 8;
#pragma unroll
    for (int ks = 0; ks < 4; ks++) qf[ks] = *(const f16x8*)(qrow + ks * 32);
  }
  const f32x4 zero = {0.f, 0.f, 0.f, 0.f};
  f32x4 O[8];
#pragma unroll
  for (int i = 0; i < 8; i++) O[i] = zero;
  float m_r[4] = {-1e30f, -1e30f, -1e30f, -1e30f};
  float l_r[4] = {0.f, 0.f, 0.f, 0.f};

  const _Float16* kg0 = qk + (size_t)(b * SEQ) * 256 + 128 + (size_t)(tid >> 4) * 256 + (tid & 15) * 8;
  const _Float16* vg0 = vt + (size_t)b * 128 * SEQ + (size_t)((tid >> 3)) * SEQ + (tid & 7) * 8;
  uint4 kp[4], vp[4];

#define LOAD_TILE(kt)                                                            \
  {                                                                              \
    const _Float16* kg = kg0 + (size_t)(kt) * 64 * 256;                          \
    const _Float16* vg = vg0 + (size_t)(kt) * 64;                                \
    _Pragma("unroll") for (int p = 0; p < 4; p++) {                              \
      kp[p] = *(const uint4*)(kg + (size_t)p * 16 * 256);                        \
      vp[p] = *(const uint4*)(vg + (size_t)p * 32 * SEQ);                        \
    }                                                                            \
  }
#define STORE_K(buf)                                                             \
  _Pragma("unroll") for (int p = 0; p < 4; p++)                                  \
      *(uint4*)&Ks[buf][(tid >> 4) + 16 * p][(tid & 15) * 8] = kp[p];
#define STORE_V()                                                                \
  _Pragma("unroll") for (int p = 0; p < 4; p++)                                  \
      *(uint4*)&Vs[(tid >> 3) + 32 * p][(tid & 7) * 8] = vp[p];

  LOAD_TILE(0);
  STORE_K(0);
  STORE_V();
  __syncthreads();

  const int NT = SEQ / 64;
  for (int kt = 0; kt < NT; kt++) {
    const int cur = kt & 1;
    if (kt + 1 < NT) LOAD_TILE(kt + 1);

    // S = Q K^T  (4 key-tiles of 16)
    f32x4 s4[4];
#pragma unroll
    for (int nt = 0; nt < 4; nt++) {
      s4[nt] = zero;
#pragma unroll
      for (int ks = 0; ks < 4; ks++) {
        f16x8 kf = *(const f16x8*)&Ks[cur][nt * 16 + l15][ks * 32 + quad * 8];
        s4[nt] = __builtin_amdgcn_mfma_f32_16x16x32_f16(qf[ks], kf, s4[nt], 0, 0, 0);
      }
    }
    // online softmax; row = quad*4 + r, spread over 16 l15 lanes
    float rmax[4], alpha[4], rsum[4];
#pragma unroll
    for (int r = 0; r < 4; r++)
      rmax[r] = fmaxf(fmaxf(s4[0][r], s4[1][r]), fmaxf(s4[2][r], s4[3][r]));
#pragma unroll
    for (int o = 1; o < 16; o <<= 1)
#pragma unroll
      for (int r = 0; r < 4; r++) rmax[r] = fmaxf(rmax[r], __shfl_xor(rmax[r], o, 64));
#pragma unroll
    for (int r = 0; r < 4; r++) {
      const float nm = fmaxf(m_r[r], rmax[r]);
      alpha[r] = __expf(m_r[r] - nm);
      m_r[r] = nm;
#pragma unroll
      for (int nt = 0; nt < 4; nt++) s4[nt][r] = __expf(s4[nt][r] - nm);
      rsum[r] = s4[0][r] + s4[1][r] + s4[2][r] + s4[3][r];
    }
#pragma unroll
    for (int o = 1; o < 16; o <<= 1)
#pragma unroll
      for (int r = 0; r < 4; r++) rsum[r] += __shfl_xor(rsum[r], o, 64);
#pragma unroll
    for (int r = 0; r < 4; r++) {
      l_r[r] = l_r[r] * alpha[r] + rsum[r];
#pragma unroll
      for (int i = 0; i < 8; i++) O[i][r] *= alpha[r];
    }
    // P -> LDS (C-layout write), read back in A-layout (same wave, in-order DS)
#pragma unroll
    for (int nt = 0; nt < 4; nt++)
#pragma unroll
      for (int r = 0; r < 4; r++)
        Ps[w][quad * 4 + r][nt * 16 + l15] = (_Float16)s4[nt][r];
    f16x8 pa[2];
#pragma unroll
    for (int ks = 0; ks < 2; ks++)
      pa[ks] = *(const f16x8*)&Ps[w][l15][ks * 32 + quad * 8];
    // O += P @ V  (8 vdim-tiles of 16)
#pragma unroll
    for (int ks = 0; ks < 2; ks++)
#pragma unroll
      for (int vt8 = 0; vt8 < 8; vt8++) {
        f16x8 vf = *(const f16x8*)&Vs[vt8 * 16 + l15][ks * 32 + quad * 8];
        O[vt8] = __builtin_amdgcn_mfma_f32_16x16x32_f16(pa[ks], vf, O[vt8], 0, 0, 0);
      }

    if (kt + 1 < NT) {
      STORE_K(cur ^ 1);        // other K buffer: safe without barrier
      __syncthreads();         // all waves done reading Vs for this tile
      STORE_V();
      __syncthreads();         // next tile K+V visible
    }
  }
  // epilogue: H[q][vd] = O / l
#pragma unroll
  for (int r = 0; r < 4; r++) {
    const float inv = 1.0f / l_r[r];
    _Float16* hp = H + (size_t)(b * SEQ + q0 + w * 16 + quad * 4 + r) * D_HEAD;
#pragma unroll
    for (int vt8 = 0; vt8 < 8; vt8++)
      hp[vt8 * 16 + l15] = (_Float16)(O[vt8][r] * inv);
  }
}

// ---------------- launch ----------------
extern "C" void kernel_launch(void* const* d_in, const int* in_sizes, int n_in,
                              void* d_out, int out_size, void* d_ws, size_t ws_size,
                              hipStream_t stream) {
  const float* x     = (const float*)d_in[0];
  const float* ln1_g = (const float*)d_in[1];
  const float* ln1_b = (const float*)d_in[2];
  const float* Wq    = (const float*)d_in[3];
  const float* bq    = (const float*)d_in[4];
  const float* Wk    = (const float*)d_in[5];
  const float* bk    = (const float*)d_in[6];
  const float* Wv    = (const float*)d_in[7];
  const float* bv    = (const float*)d_in[8];
  const float* Wo    = (const float*)d_in[9];
  const float* bo    = (const float*)d_in[10];
  const float* ln2_g = (const float*)d_in[11];
  const float* ln2_b = (const float*)d_in[12];
  const float* W1    = (const float*)d_in[13];
  const float* b1    = (const float*)d_in[14];
  const float* W2    = (const float*)d_in[15];
  const float* b2    = (const float*)d_in[16];
  float* out = (float*)d_out;

  // Workspace (<=180 MiB), lifetime-overlapped:
  //  [0,8M) W1T | [8,16M) W2T | [16,16.75M) WqkvT | [16.75,17M) WoT
  //  [20,84M) xn_f32 (K1..K4) | [84,116M) xn_f16 (K1..K2)
  //  [116,124M) qk (K2..K3) | [124,128M) vt (K2..K3) | [128,132M) Hb (K3..K4)
  //  [20,148M) act f16 (K6..K7, reuses dead buffers) | [148,180M) h16 (K5..K6)
  char* ws = (char*)d_ws;
  const size_t MB = 1024 * 1024;
  _Float16* W1T   = (_Float16*)(ws);
  _Float16* W2T   = (_Float16*)(ws + 8 * MB);
  _Float16* WqkvT = (_Float16*)(ws + 16 * MB);
  _Float16* WoT   = (_Float16*)(ws + 16 * MB + 768 * 1024);
  float*    xn_f32 = (float*)(ws + 20 * MB);
  _Float16* xn_f16 = (_Float16*)(ws + 84 * MB);
  _Float16* qkb  = (_Float16*)(ws + 116 * MB);
  _Float16* vtb  = (_Float16*)(ws + 124 * MB);
  _Float16* Hb   = (_Float16*)(ws + 128 * MB);
  _Float16* act  = (_Float16*)(ws + 20 * MB);
  _Float16* h16  = (_Float16*)(ws + 148 * MB);

  // K0: weight convert+transpose (Wq/Wk/Wv into one contiguous [384][1024])
  convt_kernel<<<dim3(D_FF / 32, D_MODEL / 32), 256, 0, stream>>>(W1, W1T, D_MODEL, D_FF);
  convt_kernel<<<dim3(D_MODEL / 32, D_FF / 32), 256, 0, stream>>>(W2, W2T, D_FF, D_MODEL);
  convt_kernel<<<dim3(D_HEAD / 32, D_MODEL / 32), 256, 0, stream>>>(Wq, WqkvT, D_MODEL, D_HEAD);
  convt_kernel<<<dim3(D_HEAD / 32, D_MODEL / 32), 256, 0, stream>>>(Wk, WqkvT + 128 * 1024, D_MODEL, D_HEAD);
  convt_kernel<<<dim3(D_HEAD / 32, D_MODEL / 32), 256, 0, stream>>>(Wv, WqkvT + 256 * 1024, D_MODEL, D_HEAD);
  convt_kernel<<<dim3(D_MODEL / 32, D_HEAD / 32), 256, 0, stream>>>(Wo, WoT, D_HEAD, D_MODEL);
  // K1: LN1
  ln_kernel<true><<<dim3(M_TOT), 256, 0, stream>>>(x, ln1_g, ln1_b, xn_f32, xn_f16);
  // K2: fused QKV projection -> qk[M][256] (q scaled) + vt[B][128][S]
  mfma_gemm<2><<<dim3(3, M_TOT / 128), 256, 0, stream>>>(
      xn_f16, WqkvT, bq, bk, bv, nullptr, qkb, vtb, M_TOT, 384, D_MODEL);
  // K3: flash attention -> Hb f16
  flash_attn_mfma<<<dim3(SEQ / 64, NBATCH), 256, 0, stream>>>(qkb, vtb, Hb);
  // K4: y = xn + H @ Wo + bo -> out f32  (4-phase 256^2 GEMM, NKT=4)
  mfma_gemm256<0><<<dim3((D_MODEL / 256) * (M_TOT / 256)), 512, 0, stream>>>(
      Hb, WoT, bo, xn_f32, out, M_TOT, D_MODEL, D_HEAD);
  // K5: LN2 -> h16
  ln_kernel<false><<<dim3(M_TOT), 256, 0, stream>>>(out, ln2_g, ln2_b, nullptr, h16);
  // K6: act = gelu(h @ W1 + b1) f16
  mfma_gemm256<1><<<dim3((D_FF / 256) * (M_TOT / 256)), 512, 0, stream>>>(
      h16, W1T, b1, nullptr, act, M_TOT, D_FF, D_MODEL);
  // K7: out = y + act @ W2 + b2
  mfma_gemm256<0><<<dim3((D_MODEL / 256) * (M_TOT / 256)), 512, 0, stream>>>(
      act, W2T, b2, out, out, M_TOT, D_MODEL, D_FF);

  (void)in_sizes; (void)n_in; (void)out_size; (void)ws_size;
}

// Round 8
// 638.368 us; speedup vs baseline: 1.0177x; 1.0177x over previous
//
#include <hip/hip_runtime.h>
#include <math.h>

// Problem constants (B=8, S=2048, D=1024, DK=DV=128, FF=4096)
#define M_TOT   16384
#define D_MODEL 1024
#define D_HEAD  128
#define SEQ     2048
#define NBATCH  8
#define D_FF    4096

typedef _Float16 f16x8 __attribute__((ext_vector_type(8)));
typedef _Float16 f16x4 __attribute__((ext_vector_type(4)));
typedef float    f32x4 __attribute__((ext_vector_type(4)));

#define ATT_SCALE 0.08838834764831845f  // 1/sqrt(128)

__device__ __forceinline__ void gload_lds16(const _Float16* g, _Float16* l) {
  __builtin_amdgcn_global_load_lds(
      (const __attribute__((address_space(1))) unsigned int*)g,
      (__attribute__((address_space(3))) unsigned int*)l, 16, 0, 0);
}
__device__ __forceinline__ unsigned short f16bits(float v) {
  union { _Float16 f; unsigned short u; } cv; cv.f = (_Float16)v; return cv.u;
}
// tanh-form GELU: 0.5x(1+tanh(0.79788456(x+0.044715x^3))); overflow-safe, ~8 VALU ops
__device__ __forceinline__ float gelu_f(float x) {
  const float t = 0.7978845608028654f * x * (1.0f + 0.044715f * x * x);
  const float e = __expf(2.0f * t);
  const float th = 1.0f - 2.0f / (e + 1.0f);
  return 0.5f * x * (1.0f + th);
}
__device__ __forceinline__ void bar_sync() {
  __asm__ volatile("" ::: "memory");
  __builtin_amdgcn_s_barrier();
  __asm__ volatile("" ::: "memory");
}
// raw ds_read_b128 with immediate offset
__device__ __forceinline__ void ds_read128o(f16x8& d, unsigned addr, int imm) {
  asm volatile("ds_read_b128 %0, %1 offset:%2" : "=v"(d) : "v"(addr), "i"(imm));
}
#define MFMA16(a, b, c) __builtin_amdgcn_mfma_f32_16x16x32_f16((a), (b), (c), 0, 0, 0)

// ---------------- weight convert + transpose: out[n][k] = f16(in[k][n]) ----------------
__global__ __launch_bounds__(256) void convt_kernel(const float* __restrict__ in,
                                                    _Float16* __restrict__ out,
                                                    int K, int N) {
  __shared__ float t[32][33];
  const int n0 = blockIdx.x * 32, k0 = blockIdx.y * 32;
  const int tx = threadIdx.x & 31, ty = threadIdx.x >> 5;   // 32 x 8
#pragma unroll
  for (int r = 0; r < 4; r++)
    t[ty + 8 * r][tx] = in[(size_t)(k0 + ty + 8 * r) * N + n0 + tx];
  __syncthreads();
#pragma unroll
  for (int r = 0; r < 4; r++)
    out[(size_t)(n0 + ty + 8 * r) * K + k0 + tx] = (_Float16)t[tx][ty + 8 * r];
}

// ---------------- LayerNorm: one block (256 thr) per row of 1024 ----------------
template <bool WF32>
__global__ __launch_bounds__(256) void ln_kernel(const float* __restrict__ in,
                                                 const float* __restrict__ gamma,
                                                 const float* __restrict__ beta,
                                                 float* __restrict__ of,
                                                 _Float16* __restrict__ oh) {
  __shared__ float shs[4], shq[4];
  const int row = blockIdx.x;
  const int t = threadIdx.x;
  float4 v = ((const float4*)(in + (size_t)row * D_MODEL))[t];
  float s = v.x + v.y + v.z + v.w;
  float q = v.x * v.x + v.y * v.y + v.z * v.z + v.w * v.w;
#pragma unroll
  for (int o = 32; o > 0; o >>= 1) {
    s += __shfl_down(s, o, 64);
    q += __shfl_down(q, o, 64);
  }
  const int lane = t & 63, w = t >> 6;
  if (lane == 0) { shs[w] = s; shq[w] = q; }
  __syncthreads();
  if (t == 0) {
    shs[0] = shs[0] + shs[1] + shs[2] + shs[3];
    shq[0] = shq[0] + shq[1] + shq[2] + shq[3];
  }
  __syncthreads();
  const float mu = shs[0] * (1.0f / D_MODEL);
  const float var = shq[0] * (1.0f / D_MODEL) - mu * mu;
  const float rs = rsqrtf(var + 1e-5f);
  float4 gv = ((const float4*)gamma)[t];
  float4 bv = ((const float4*)beta)[t];
  float4 o;
  o.x = (v.x - mu) * rs * gv.x + bv.x;
  o.y = (v.y - mu) * rs * gv.y + bv.y;
  o.z = (v.z - mu) * rs * gv.z + bv.z;
  o.w = (v.w - mu) * rs * gv.w + bv.w;
  if (WF32) ((float4*)(of + (size_t)row * D_MODEL))[t] = o;
  f16x4 h4 = {(_Float16)o.x, (_Float16)o.y, (_Float16)o.z, (_Float16)o.w};
  ((f16x4*)(oh + (size_t)row * D_MODEL))[t] = h4;
}

// =====================================================================================
// 256x256-tile MFMA GEMM — faithful m201 8-phase port. BK=64, 512 thr = 8 waves (2Mx4N),
// LDS [dbuf=2][op A/B][half=2][128 rows][64 cols] f16 = 128 KiB. Iter = 2 K-tiles =
// 8 phases; per phase: {ds_reads (12/4/8/0) ; stage 1 half-tile (2 gloads) ; barrier ;
// lgkmcnt(0)+sched_barrier ; setprio(1) ; 16 MFMA ; setprio(0) ; barrier}; counted
// vmcnt(4) ONLY at phases 4 and 8. Chunk swizzle phys_chunk = (c>>3)^(r&7) — staged via
// pre-permuted global source (linear LDS dest), read via XOR'd ds addr; conflict-free.
// A f16 [M][K], BT f16 [N][K].
// MODE 0: C f32 = acc + bias[col] + res ; MODE 1: C f16 = gelu(acc + bias[col])
// Requires: M%256==0, N%256==0, K%128==0 (NKT=K/64 even >=2), gridDim.x%8==0.
// =====================================================================================

// stage one 1-KiB slice: half-tile (op, H) of K-tile JT into dbuf D; wave covers rows
// P*64 + w*8 + (lane>>3), global col pre-permuted by ((lane&7)^(lane>>3))*8.
#define STGA(D, H, P, JT)                                                     \
  gload_lds16(Ag0 + (size_t)((H) * 128 + (P) * 64) * K + (size_t)(JT) * 64,   \
              SM + (D) * 32768 + (H) * 8192 + (P) * 4096 + wld)
#define STGB(D, H, P, JT)                                                     \
  gload_lds16(Bg0 + (size_t)((H) * 128 + (P) * 64) * K + (size_t)(JT) * 64,   \
              SM + (D) * 32768 + 16384 + (H) * 8192 + (P) * 4096 + wld)

// frag reads: A half-m MH (4 m x 2 kk = 8 reads) / B half-n NH (2 n x 2 kk = 4 reads)
#define RD_A(D, MH)                                                           \
  _Pragma("unroll") for (int mi = 0; mi < 4; ++mi) {                          \
    ds_read128o(fa[mi][0], bA[D][0], ((MH) * 4 + mi) * 2048);                 \
    ds_read128o(fa[mi][1], bA[D][1], ((MH) * 4 + mi) * 2048);                 \
  }
#define RD_B(D, NH)                                                           \
  _Pragma("unroll") for (int ni = 0; ni < 2; ++ni) {                          \
    ds_read128o(fb[(NH) * 2 + ni][0], bB[D][0], ((NH) * 2 + ni) * 2048);      \
    ds_read128o(fb[(NH) * 2 + ni][1], bB[D][1], ((NH) * 2 + ni) * 2048);      \
  }
// one C-quadrant x K=64: 16 MFMA
#define PH_MFMA(MH, NH)                                                       \
  bar_sync();                                                                 \
  asm volatile("s_waitcnt lgkmcnt(0)" ::: "memory");                          \
  __builtin_amdgcn_sched_barrier(0);                                          \
  __builtin_amdgcn_s_setprio(1);                                              \
  _Pragma("unroll") for (int mi = 0; mi < 4; ++mi)                            \
    _Pragma("unroll") for (int ni = 0; ni < 2; ++ni) {                        \
      acc[(MH) * 4 + mi][(NH) * 2 + ni] =                                     \
          MFMA16(fa[mi][0], fb[(NH) * 2 + ni][0], acc[(MH) * 4 + mi][(NH) * 2 + ni]); \
      acc[(MH) * 4 + mi][(NH) * 2 + ni] =                                     \
          MFMA16(fa[mi][1], fb[(NH) * 2 + ni][1], acc[(MH) * 4 + mi][(NH) * 2 + ni]); \
    }                                                                         \
  __builtin_amdgcn_s_setprio(0);

#define VMW(N)                                                                \
  if ((N) == 4) { asm volatile("s_waitcnt vmcnt(4)" ::: "memory"); }          \
  if ((N) == 0) { asm volatile("s_waitcnt vmcnt(0)" ::: "memory"); }

// One iteration: K-tile J (dbuf0, phases 1-4) + K-tile J+1 (dbuf1, phases 5-8).
// Stage schedule (WAR/RAW ledger verified): A(J+1)->d1 @ph1,2 ; B(J+2)->d0 @ph3,4 ;
// A(J+2)->d0 @ph5,6 ; B(J+3)->d1 @ph7,8. vmcnt(4)@ph4 retires prev-B + A(J+1);
// vmcnt(4)@ph8 retires B(J+2)+A(J+2).
#define ITER8(J, SA1, SB2, SA2, SB3, VM4, VM8)                                \
  {                                                                           \
    /* ph1 */                                                                 \
    RD_A(0, 0); RD_B(0, 0);                                                   \
    if (SA1) { STGA(1, 0, 0, (J) + 1); STGA(1, 0, 1, (J) + 1); }              \
    PH_MFMA(0, 0); bar_sync();                                                \
    /* ph2 */                                                                 \
    RD_B(0, 1);                                                               \
    if (SA1) { STGA(1, 1, 0, (J) + 1); STGA(1, 1, 1, (J) + 1); }              \
    PH_MFMA(0, 1); bar_sync();                                                \
    /* ph3 */                                                                 \
    RD_A(0, 1);                                                               \
    if (SB2) { STGB(0, 0, 0, (J) + 2); STGB(0, 0, 1, (J) + 2); }              \
    PH_MFMA(1, 0); bar_sync();                                                \
    /* ph4 */                                                                 \
    if (SB2) { STGB(0, 1, 0, (J) + 2); STGB(0, 1, 1, (J) + 2); }              \
    PH_MFMA(1, 1); VMW(VM4); bar_sync();                                      \
    /* ph5 */                                                                 \
    RD_A(1, 0); RD_B(1, 0);                                                   \
    if (SA2) { STGA(0, 0, 0, (J) + 2); STGA(0, 0, 1, (J) + 2); }              \
    PH_MFMA(0, 0); bar_sync();                                                \
    /* ph6 */                                                                 \
    RD_B(1, 1);                                                               \
    if (SA2) { STGA(0, 1, 0, (J) + 2); STGA(0, 1, 1, (J) + 2); }              \
    PH_MFMA(0, 1); bar_sync();                                                \
    /* ph7 */                                                                 \
    RD_A(1, 1);                                                               \
    if (SB3) { STGB(1, 0, 0, (J) + 3); STGB(1, 0, 1, (J) + 3); }              \
    PH_MFMA(1, 0); bar_sync();                                                \
    /* ph8 */                                                                 \
    if (SB3) { STGB(1, 1, 0, (J) + 3); STGB(1, 1, 1, (J) + 3); }              \
    PH_MFMA(1, 1); VMW(VM8); bar_sync();                                      \
  }

template <int MODE>
__global__ __launch_bounds__(512, 2) void mfma_gemm256(
    const _Float16* __restrict__ A, const _Float16* __restrict__ BT,
    const float* __restrict__ bias, const float* __restrict__ res,
    void* __restrict__ Cout, int M, int N, int K) {
  __shared__ __attribute__((aligned(16))) _Float16 SM[2 * 32768];  // 128 KiB
  const int tid = threadIdx.x;
  const int lane = tid & 63, w = tid >> 6;
  const int l15 = lane & 15, quad = lane >> 4;
  const int wm = w >> 2, wn = w & 3;

  // T1: XCD-aware swizzle (consecutive logical ids -> same XCD; gridDim.x%8==0)
  const int nwg = gridDim.x;
  const int bid = (blockIdx.x & 7) * (nwg >> 3) + (blockIdx.x >> 3);
  const int nbx = N >> 8;
  const int bx = bid % nbx, by = bid / nbx;
  const int row0 = by << 8, col0 = bx << 8;

  // staging lane constants: lane L covers row +L>>3, pre-permuted col ((L&7)^(L>>3))*8
  const int lrS = lane >> 3;
  const int lcS = ((lane & 7) ^ lrS) * 8;
  const _Float16* Ag0 = A + (size_t)(row0 + w * 8 + lrS) * K + lcS;
  const _Float16* Bg0 = BT + (size_t)(col0 + w * 8 + lrS) * K + lcS;
  const int wld = w * 512;   // f16 units (1 KiB per wave slice)

  // frag-read bases: phys_byte = r*128 + (((kk<<2|quad)^(r&7))<<4); r&7 == l15&7 for
  // all frag rows (m*16 steps). A half = wm; B half = wn>>1, +((wn&1)*64 rows).
  const unsigned lds0 =
      (unsigned)(size_t)(__attribute__((address_space(3))) _Float16*)&SM[0];
  const unsigned l7 = (unsigned)(l15 & 7);
  const unsigned laneRowB = (unsigned)l15 << 7;
  unsigned bA[2][2], bB[2][2];
#pragma unroll
  for (int d = 0; d < 2; ++d)
#pragma unroll
    for (int kk = 0; kk < 2; ++kk) {
      const unsigned ch = (((unsigned)((kk << 2) | quad)) ^ l7) << 4;
      bA[d][kk] = lds0 + (unsigned)d * 65536u + (unsigned)wm * 16384u + laneRowB + ch;
      bB[d][kk] = lds0 + (unsigned)d * 65536u + 32768u + (unsigned)(wn >> 1) * 16384u +
                  (unsigned)(wn & 1) * 8192u + laneRowB + ch;
    }

  const f32x4 zero = {0.f, 0.f, 0.f, 0.f};
  f32x4 acc[8][4];
#pragma unroll
  for (int m = 0; m < 8; ++m)
#pragma unroll
    for (int n = 0; n < 4; ++n) acc[m][n] = zero;
  f16x8 fa[4][2], fb[4][2];

  const int NKT = K >> 6;        // K-tiles of 64; even, >= 2
  const int niter = NKT >> 1;

  // prologue: stage A(0) [4 loads], B(0) [4], B(1) [4]; retire first 8 -> vmcnt(4)
#pragma unroll
  for (int h = 0; h < 2; ++h) { STGA(0, h, 0, 0); STGA(0, h, 1, 0); }
#pragma unroll
  for (int h = 0; h < 2; ++h) { STGB(0, h, 0, 0); STGB(0, h, 1, 0); }
#pragma unroll
  for (int h = 0; h < 2; ++h) { STGB(1, h, 0, 1); STGB(1, h, 1, 1); }
  asm volatile("s_waitcnt vmcnt(4)" ::: "memory");
  bar_sync();

#pragma unroll 1
  for (int i = 0; i + 1 < niter; ++i) { ITER8(2 * i, 1, 1, 1, 1, 4, 4); }
  // last iteration (J = NKT-2): only A(NKT-1) still needed; drain at ph4.
  ITER8(NKT - 2, 1, 0, 0, 0, 0, -1);

  // epilogue. C/D layout: col = l15, row = quad*4 + r  [verified earlier rounds]
  const int colb = col0 + wn * 64 + l15;
  if (MODE == 0) {
    float* C = (float*)Cout;
    float bv[4];
#pragma unroll
    for (int n = 0; n < 4; ++n) bv[n] = bias[colb + n * 16];
#pragma unroll
    for (int m = 0; m < 8; ++m)
#pragma unroll
      for (int r = 0; r < 4; ++r) {
        const int row = row0 + wm * 128 + m * 16 + quad * 4 + r;
        const size_t base = (size_t)row * N + colb;
        const float* rp2 = res + base;
        float* cp = C + base;
#pragma unroll
        for (int n = 0; n < 4; ++n) cp[n * 16] = acc[m][n][r] + bv[n] + rp2[n * 16];
      }
  } else {
    _Float16* C = (_Float16*)Cout;
    float bv[4];
#pragma unroll
    for (int n = 0; n < 4; ++n) bv[n] = bias[colb + n * 16];
#pragma unroll
    for (int m = 0; m < 8; ++m)
#pragma unroll
      for (int r = 0; r < 4; ++r) {
        const int row = row0 + wm * 128 + m * 16 + quad * 4 + r;
        _Float16* cp = C + (size_t)row * N + colb;
#pragma unroll
        for (int n = 0; n < 4; ++n) cp[n * 16] = (_Float16)gelu_f(acc[m][n][r] + bv[n]);
      }
  }
  (void)M;
}

// ---------------- old 128x128 MFMA GEMM (kept for fused QKV, MODE 2) ----------------
template <int MODE>
__global__ __launch_bounds__(256) void mfma_gemm(const _Float16* __restrict__ A,
                                                 const _Float16* __restrict__ BT,
                                                 const float* __restrict__ b0p,
                                                 const float* __restrict__ b1p,
                                                 const float* __restrict__ b2p,
                                                 const float* __restrict__ res,
                                                 void* __restrict__ Cout,
                                                 _Float16* __restrict__ vtout,
                                                 int M, int N, int K) {
  __shared__ _Float16 SMEM[2 * 128 * 32];   // As | Bs ; aliased as Ts in MODE2-V epilogue
  _Float16* As = SMEM;
  _Float16* Bs = SMEM + 128 * 32;
  const int tid = threadIdx.x;
  const int lane = tid & 63, w = tid >> 6;
  const int wr = w >> 1, wc = w & 1;
  const int row0 = blockIdx.y << 7, col0 = blockIdx.x << 7;
  const int l15 = lane & 15, quad = lane >> 4;
  const f32x4 zero = {0.f, 0.f, 0.f, 0.f};
  f32x4 acc[4][4];
#pragma unroll
  for (int i = 0; i < 4; i++)
#pragma unroll
    for (int j = 0; j < 4; j++) acc[i][j] = zero;

  const int srow = lane >> 2;          // 0..15
  const int scol = (lane & 3) << 3;    // 0,8,16,24
  const _Float16* Ag = A + (size_t)(row0 + w * 32 + srow) * K + scol;
  const _Float16* Bg = BT + (size_t)(col0 + w * 32 + srow) * K + scol;

  for (int k0 = 0; k0 < K; k0 += 32) {
#pragma unroll
    for (int p = 0; p < 2; p++) {
      gload_lds16(Ag + (size_t)(p * 16) * K + k0, &As[(w * 32 + p * 16) * 32]);
      gload_lds16(Bg + (size_t)(p * 16) * K + k0, &Bs[(w * 32 + p * 16) * 32]);
    }
    __syncthreads();
    f16x8 af[4], bfr[4];
#pragma unroll
    for (int i = 0; i < 4; i++) {
      af[i]  = *(const f16x8*)&As[(wr * 64 + i * 16 + l15) * 32 + quad * 8];
      bfr[i] = *(const f16x8*)&Bs[(wc * 64 + i * 16 + l15) * 32 + quad * 8];
    }
#pragma unroll
    for (int i = 0; i < 4; i++)
#pragma unroll
      for (int j = 0; j < 4; j++)
        acc[i][j] = __builtin_amdgcn_mfma_f32_16x16x32_f16(af[i], bfr[j], acc[i][j], 0, 0, 0);
    __syncthreads();
  }

  // Epilogue. C/D layout: col = l15, row = quad*4 + r
  if (MODE == 0) {
    float* C = (float*)Cout;
    float bv4[4];
#pragma unroll
    for (int j = 0; j < 4; j++) bv4[j] = b0p[col0 + wc * 64 + j * 16 + l15];
#pragma unroll
    for (int i = 0; i < 4; i++)
#pragma unroll
      for (int r = 0; r < 4; r++) {
        const int row = row0 + wr * 64 + i * 16 + quad * 4 + r;
        const size_t base = (size_t)row * N + col0 + wc * 64 + l15;
        const float* rp = res + base;
        float* cp = C + base;
#pragma unroll
        for (int j = 0; j < 4; j++)
          cp[j * 16] = acc[i][j][r] + bv4[j] + rp[j * 16];
      }
  } else if (MODE == 1) {
    _Float16* C = (_Float16*)Cout;
    float bv4[4];
#pragma unroll
    for (int j = 0; j < 4; j++) bv4[j] = b0p[col0 + wc * 64 + j * 16 + l15];
#pragma unroll
    for (int i = 0; i < 4; i++)
#pragma unroll
      for (int r = 0; r < 4; r++) {
        const int row = row0 + wr * 64 + i * 16 + quad * 4 + r;
        _Float16* cp = C + (size_t)row * N + col0 + wc * 64 + l15;
#pragma unroll
        for (int j = 0; j < 4; j++)
          cp[j * 16] = (_Float16)gelu_f(acc[i][j][r] + bv4[j]);
      }
  } else {
    _Float16* qkout = (_Float16*)Cout;
    const int bx = blockIdx.x;
    if (bx < 2) {
      // q (scaled) or k -> qk[M][256]
      const float* bp = (bx == 0) ? b0p : b1p;
      const float sc = (bx == 0) ? ATT_SCALE : 1.0f;
      const int cofs = bx * 128 + wc * 64 + l15;
      float bv4[4];
#pragma unroll
      for (int j = 0; j < 4; j++) bv4[j] = bp[wc * 64 + j * 16 + l15];
#pragma unroll
      for (int i = 0; i < 4; i++)
#pragma unroll
        for (int r = 0; r < 4; r++) {
          const int row = row0 + wr * 64 + i * 16 + quad * 4 + r;
          _Float16* cp = qkout + (size_t)row * 256 + cofs;
#pragma unroll
          for (int j = 0; j < 4; j++)
            cp[j * 16] = (_Float16)((acc[i][j][r] + bv4[j]) * sc);
        }
    } else {
      // v -> vt[B][128][S], via LDS transpose (Ts[vd][40] f16, aliases SMEM)
      _Float16* Ts = SMEM;
      float bv4[4];
#pragma unroll
      for (int j = 0; j < 4; j++) bv4[j] = b2p[wc * 64 + j * 16 + l15];
      const int bb = row0 >> 11, s0 = row0 & 2047;
#pragma unroll
      for (int c = 0; c < 4; c++) {        // s-chunk [c*32, c*32+32)
        __syncthreads();
        if (wr == (c >> 1)) {
#pragma unroll
          for (int ii = 0; ii < 2; ii++) {
            const int i = (c & 1) * 2 + ii;
#pragma unroll
            for (int j = 0; j < 4; j++) {
              const int vd = wc * 64 + j * 16 + l15;
              const int slocal = ii * 16 + quad * 4;
              ushort4 h;
              h.x = f16bits(acc[i][j][0] + bv4[j]);
              h.y = f16bits(acc[i][j][1] + bv4[j]);
              h.z = f16bits(acc[i][j][2] + bv4[j]);
              h.w = f16bits(acc[i][j][3] + bv4[j]);
              *(ushort4*)&Ts[vd * 40 + slocal] = h;
            }
          }
        }
        __syncthreads();
#pragma unroll
        for (int p = 0; p < 2; p++) {
          const int idx = tid + p * 256;       // 0..511
          const int vd = idx >> 2, s8 = (idx & 3) * 8;
          uint4 d = *(const uint4*)&Ts[vd * 40 + s8];
          *(uint4*)&vtout[((size_t)bb * 128 + vd) * SEQ + s0 + c * 32 + s8] = d;
        }
      }
    }
  }
}

// ---------------- MFMA flash attention ----------------
// Grid (SEQ/64, B), 256 thr = 4 waves, 16 queries/wave. 64-key tiles.
// qk: [B*S][256] f16 (q pre-scaled, k). vt: [B][128][S] f16. H: [B*S][128] f16.
__global__ __launch_bounds__(256) void flash_attn_mfma(const _Float16* __restrict__ qk,
                                                       const _Float16* __restrict__ vt,
                                                       _Float16* __restrict__ H) {
  __shared__ _Float16 Ks[2][64][136];   // keys x d, pad 8
  __shared__ _Float16 Vs[128][72];      // d x keys, pad 8
  __shared__ _Float16 Ps[4][16][72];    // per-wave P: q x keys, pad 8
  const int b = blockIdx.y, q0 = blockIdx.x * 64;
  const int tid = threadIdx.x;
  const int lane = tid & 63, w = tid >> 6;
  const int l15 = lane & 15, quad = lane >> 4;

  // Q fragments (A-layout), q pre-scaled by 1/sqrt(dk)
  f16x8 qf[4];
  {
    const _Float16* qrow = qk + ((size_t)(b * SEQ + q0 + w * 16 + l15)) * 256 + quad * 8;
#pragma unroll
    for (int ks = 0; ks < 4; ks++) qf[ks] = *(const f16x8*)(qrow + ks * 32);
  }
  const f32x4 zero = {0.f, 0.f, 0.f, 0.f};
  f32x4 O[8];
#pragma unroll
  for (int i = 0; i < 8; i++) O[i] = zero;
  float m_r[4] = {-1e30f, -1e30f, -1e30f, -1e30f};
  float l_r[4] = {0.f, 0.f, 0.f, 0.f};

  const _Float16* kg0 = qk + (size_t)(b * SEQ) * 256 + 128 + (size_t)(tid >> 4) * 256 + (tid & 15) * 8;
  const _Float16* vg0 = vt + (size_t)b * 128 * SEQ + (size_t)((tid >> 3)) * SEQ + (tid & 7) * 8;
  uint4 kp[4], vp[4];

#define LOAD_TILE(kt)                                                            \
  {                                                                              \
    const _Float16* kg = kg0 + (size_t)(kt) * 64 * 256;                          \
    const _Float16* vg = vg0 + (size_t)(kt) * 64;                                \
    _Pragma("unroll") for (int p = 0; p < 4; p++) {                              \
      kp[p] = *(const uint4*)(kg + (size_t)p * 16 * 256);                        \
      vp[p] = *(const uint4*)(vg + (size_t)p * 32 * SEQ);                        \
    }                                                                            \
  }
#define STORE_K(buf)                                                             \
  _Pragma("unroll") for (int p = 0; p < 4; p++)                                  \
      *(uint4*)&Ks[buf][(tid >> 4) + 16 * p][(tid & 15) * 8] = kp[p];
#define STORE_V()                                                                \
  _Pragma("unroll") for (int p = 0; p < 4; p++)                                  \
      *(uint4*)&Vs[(tid >> 3) + 32 * p][(tid & 7) * 8] = vp[p];

  LOAD_TILE(0);
  STORE_K(0);
  STORE_V();
  __syncthreads();

  const int NT = SEQ / 64;
  for (int kt = 0; kt < NT; kt++) {
    const int cur = kt & 1;
    if (kt + 1 < NT) LOAD_TILE(kt + 1);

    // S = Q K^T  (4 key-tiles of 16)
    f32x4 s4[4];
#pragma unroll
    for (int nt = 0; nt < 4; nt++) {
      s4[nt] = zero;
#pragma unroll
      for (int ks = 0; ks < 4; ks++) {
        f16x8 kf = *(const f16x8*)&Ks[cur][nt * 16 + l15][ks * 32 + quad * 8];
        s4[nt] = __builtin_amdgcn_mfma_f32_16x16x32_f16(qf[ks], kf, s4[nt], 0, 0, 0);
      }
    }
    // online softmax; row = quad*4 + r, spread over 16 l15 lanes
    float rmax[4], alpha[4], rsum[4];
#pragma unroll
    for (int r = 0; r < 4; r++)
      rmax[r] = fmaxf(fmaxf(s4[0][r], s4[1][r]), fmaxf(s4[2][r], s4[3][r]));
#pragma unroll
    for (int o = 1; o < 16; o <<= 1)
#pragma unroll
      for (int r = 0; r < 4; r++) rmax[r] = fmaxf(rmax[r], __shfl_xor(rmax[r], o, 64));
#pragma unroll
    for (int r = 0; r < 4; r++) {
      const float nm = fmaxf(m_r[r], rmax[r]);
      alpha[r] = __expf(m_r[r] - nm);
      m_r[r] = nm;
#pragma unroll
      for (int nt = 0; nt < 4; nt++) s4[nt][r] = __expf(s4[nt][r] - nm);
      rsum[r] = s4[0][r] + s4[1][r] + s4[2][r] + s4[3][r];
    }
#pragma unroll
    for (int o = 1; o < 16; o <<= 1)
#pragma unroll
      for (int r = 0; r < 4; r++) rsum[r] += __shfl_xor(rsum[r], o, 64);
#pragma unroll
    for (int r = 0; r < 4; r++) {
      l_r[r] = l_r[r] * alpha[r] + rsum[r];
#pragma unroll
      for (int i = 0; i < 8; i++) O[i][r] *= alpha[r];
    }
    // P -> LDS (C-layout write), read back in A-layout (same wave, in-order DS)
#pragma unroll
    for (int nt = 0; nt < 4; nt++)
#pragma unroll
      for (int r = 0; r < 4; r++)
        Ps[w][quad * 4 + r][nt * 16 + l15] = (_Float16)s4[nt][r];
    f16x8 pa[2];
#pragma unroll
    for (int ks = 0; ks < 2; ks++)
      pa[ks] = *(const f16x8*)&Ps[w][l15][ks * 32 + quad * 8];
    // O += P @ V  (8 vdim-tiles of 16)
#pragma unroll
    for (int ks = 0; ks < 2; ks++)
#pragma unroll
      for (int vt8 = 0; vt8 < 8; vt8++) {
        f16x8 vf = *(const f16x8*)&Vs[vt8 * 16 + l15][ks * 32 + quad * 8];
        O[vt8] = __builtin_amdgcn_mfma_f32_16x16x32_f16(pa[ks], vf, O[vt8], 0, 0, 0);
      }

    if (kt + 1 < NT) {
      STORE_K(cur ^ 1);        // other K buffer: safe without barrier
      __syncthreads();         // all waves done reading Vs for this tile
      STORE_V();
      __syncthreads();         // next tile K+V visible
    }
  }
  // epilogue: H[q][vd] = O / l
#pragma unroll
  for (int r = 0; r < 4; r++) {
    const float inv = 1.0f / l_r[r];
    _Float16* hp = H + (size_t)(b * SEQ + q0 + w * 16 + quad * 4 + r) * D_HEAD;
#pragma unroll
    for (int vt8 = 0; vt8 < 8; vt8++)
      hp[vt8 * 16 + l15] = (_Float16)(O[vt8][r] * inv);
  }
}

// ---------------- launch ----------------
extern "C" void kernel_launch(void* const* d_in, const int* in_sizes, int n_in,
                              void* d_out, int out_size, void* d_ws, size_t ws_size,
                              hipStream_t stream) {
  const float* x     = (const float*)d_in[0];
  const float* ln1_g = (const float*)d_in[1];
  const float* ln1_b = (const float*)d_in[2];
  const float* Wq    = (const float*)d_in[3];
  const float* bq    = (const float*)d_in[4];
  const float* Wk    = (const float*)d_in[5];
  const float* bk    = (const float*)d_in[6];
  const float* Wv    = (const float*)d_in[7];
  const float* bv    = (const float*)d_in[8];
  const float* Wo    = (const float*)d_in[9];
  const float* bo    = (const float*)d_in[10];
  const float* ln2_g = (const float*)d_in[11];
  const float* ln2_b = (const float*)d_in[12];
  const float* W1    = (const float*)d_in[13];
  const float* b1    = (const float*)d_in[14];
  const float* W2    = (const float*)d_in[15];
  const float* b2    = (const float*)d_in[16];
  float* out = (float*)d_out;

  // Workspace (<=180 MiB), lifetime-overlapped:
  //  [0,8M) W1T | [8,16M) W2T | [16,16.75M) WqkvT | [16.75,17M) WoT
  //  [20,84M) xn_f32 (K1..K4) | [84,116M) xn_f16 (K1..K2)
  //  [116,124M) qk (K2..K3) | [124,128M) vt (K2..K3) | [128,132M) Hb (K3..K4)
  //  [20,148M) act f16 (K6..K7, reuses dead buffers) | [148,180M) h16 (K5..K6)
  char* ws = (char*)d_ws;
  const size_t MB = 1024 * 1024;
  _Float16* W1T   = (_Float16*)(ws);
  _Float16* W2T   = (_Float16*)(ws + 8 * MB);
  _Float16* WqkvT = (_Float16*)(ws + 16 * MB);
  _Float16* WoT   = (_Float16*)(ws + 16 * MB + 768 * 1024);
  float*    xn_f32 = (float*)(ws + 20 * MB);
  _Float16* xn_f16 = (_Float16*)(ws + 84 * MB);
  _Float16* qkb  = (_Float16*)(ws + 116 * MB);
  _Float16* vtb  = (_Float16*)(ws + 124 * MB);
  _Float16* Hb   = (_Float16*)(ws + 128 * MB);
  _Float16* act  = (_Float16*)(ws + 20 * MB);
  _Float16* h16  = (_Float16*)(ws + 148 * MB);

  // K0: weight convert+transpose (Wq/Wk/Wv into one contiguous [384][1024])
  convt_kernel<<<dim3(D_FF / 32, D_MODEL / 32), 256, 0, stream>>>(W1, W1T, D_MODEL, D_FF);
  convt_kernel<<<dim3(D_MODEL / 32, D_FF / 32), 256, 0, stream>>>(W2, W2T, D_FF, D_MODEL);
  convt_kernel<<<dim3(D_HEAD / 32, D_MODEL / 32), 256, 0, stream>>>(Wq, WqkvT, D_MODEL, D_HEAD);
  convt_kernel<<<dim3(D_HEAD / 32, D_MODEL / 32), 256, 0, stream>>>(Wk, WqkvT + 128 * 1024, D_MODEL, D_HEAD);
  convt_kernel<<<dim3(D_HEAD / 32, D_MODEL / 32), 256, 0, stream>>>(Wv, WqkvT + 256 * 1024, D_MODEL, D_HEAD);
  convt_kernel<<<dim3(D_MODEL / 32, D_HEAD / 32), 256, 0, stream>>>(Wo, WoT, D_HEAD, D_MODEL);
  // K1: LN1
  ln_kernel<true><<<dim3(M_TOT), 256, 0, stream>>>(x, ln1_g, ln1_b, xn_f32, xn_f16);
  // K2: fused QKV projection -> qk[M][256] (q scaled) + vt[B][128][S]
  mfma_gemm<2><<<dim3(3, M_TOT / 128), 256, 0, stream>>>(
      xn_f16, WqkvT, bq, bk, bv, nullptr, qkb, vtb, M_TOT, 384, D_MODEL);
  // K3: flash attention -> Hb f16
  flash_attn_mfma<<<dim3(SEQ / 64, NBATCH), 256, 0, stream>>>(qkb, vtb, Hb);
  // K4: y = xn + H @ Wo + bo -> out f32  (8-phase 256^2 GEMM, NKT=2)
  mfma_gemm256<0><<<dim3((D_MODEL / 256) * (M_TOT / 256)), 512, 0, stream>>>(
      Hb, WoT, bo, xn_f32, out, M_TOT, D_MODEL, D_HEAD);
  // K5: LN2 -> h16
  ln_kernel<false><<<dim3(M_TOT), 256, 0, stream>>>(out, ln2_g, ln2_b, nullptr, h16);
  // K6: act = gelu(h @ W1 + b1) f16
  mfma_gemm256<1><<<dim3((D_FF / 256) * (M_TOT / 256)), 512, 0, stream>>>(
      h16, W1T, b1, nullptr, act, M_TOT, D_FF, D_MODEL);
  // K7: out = y + act @ W2 + b2
  mfma_gemm256<0><<<dim3((D_MODEL / 256) * (M_TOT / 256)), 512, 0, stream>>>(
      act, W2T, b2, out, out, M_TOT, D_MODEL, D_FF);

  (void)in_sizes; (void)n_in; (void)out_size; (void)ws_size;
}